// Round 6
// baseline (197.375 us; speedup 1.0000x reference)
//
#include <hip/hip_runtime.h>

// DynamicDilationUnfold: B=4, C=64, H=W=128, G=4, Cg=16, K=3, stride=1, pad=1.
// out[b][((g*Cg+cg)*K+kh)*K+kw][ho*Wo+wo], fp32.
//
// R10 = R9 with the row off-by-one FIXED (R9 never tested its theory: region
// row coordinate is (row0+8j)+kh*d, NOT +1 -- the column +1 comes from
// pw_img = wo-1+kw*d vs region origin col -1; the row -1 is already folded
// into the region origin row ho0-1).
//
// Theory under test (write-STREAM restructure): ladder so far --
// 32w/256B=76 (R4) = 24w/256B=76 (R5), 16w/4K=106 (R6), 8w/16K=91.5 (R7),
// 32w/8K=74.7 (R8). Run size and occupancy exonerated; invariant = every
// wave interleaves writes over many 64KiB-strided planes -> thousands of
// <=512B concurrent write streams -> L2 dirty-fragment eviction -> HBM row
// thrash (~2.2 TB/s vs 6.7 fill). This version: block = (b, g, cg, half).
// Block output = its cg's 9 CONSECUTIVE planes, each a contiguous 32-KiB
// half-plane written in 8 back-to-back 4-KiB wave bursts -> ~64 sequential
// 32-KiB streams per XCD instead of ~4096 x 512B.
//   - stage 1 channel 71x135 (zero halo) in LDS, stride 137 (odd ->
//     lane-stride-1 gather ~2-way conflicts, free per m136)
//   - d loaded once into 8 VGPRs/thread (fixed wo per thread, rows +8j)
//   - 1024 thr, __launch_bounds__(1024,8): 64-VGPR cap, 38.9 KB LDS ->
//     2 blocks/CU = 32 waves/CU (R4/R8-proven occupancy)
// Weights not shared across channels (VALU ~2x, ~10us, non-critical).

constexpr int B  = 4;
constexpr int C  = 64;
constexpr int H  = 128;
constexpr int W  = 128;
constexpr int G  = 4;
constexpr int Cg = C / G;            // 16
constexpr int K  = 3;
constexpr int KK = K * K;
constexpr int Ho = 128;
constexpr int Wo = 128;
constexpr int HW = H * W;
constexpr int HoWo = Ho * Wo;

constexpr int TILE_H = 64;           // output rows per block (half plane)
constexpr int REG_H  = 71;           // image rows ho0-1 .. ho0+69 (ph_reg < 69)
constexpr int REG_W  = 135;          // image cols -1 .. 133    (pw_reg < 133)
constexpr int LDS_STRIDE = 137;      // odd: row-decorrelated banks
constexpr int NSTAGE_SRC = REG_H * REG_W;        // 9585 staged elements
constexpr int NTHREADS   = 1024;

__global__ __launch_bounds__(NTHREADS, 8) void ddu_kernel(
    const float* __restrict__ x,      // (B, C, H, W)
    const float* __restrict__ dmap,   // (B, G, H, W)
    float* __restrict__ out)          // (B, C*K*K, Ho*Wo)
{
    __shared__ float lds[REG_H * LDS_STRIDE];    // 71*137*4 = 38,908 B

    const int tid  = threadIdx.x;
    const int bid  = blockIdx.x;                 // 512 = b(4) g(4) cg(16) half(2)
    const int half = bid & 1;
    const int cg   = (bid >> 1) & 15;
    const int g    = (bid >> 5) & 3;
    const int b    = bid >> 7;

    const int ho0 = half * TILE_H;

    const float* __restrict__ xc = x + (size_t)(b * C + g * Cg + cg) * HW;

    // ---- stage one channel: rows ho0-1..ho0+69, cols -1..133, zero halo ----
#pragma unroll
    for (int it = 0; it < (NSTAGE_SRC + NTHREADS - 1) / NTHREADS; ++it) {
        const int p = it * NTHREADS + tid;
        if (p < NSTAGE_SRC) {
            const int r  = p / REG_W;
            const int c  = p - r * REG_W;
            const int ir = ho0 - 1 + r;
            const int ic = c - 1;
            float v = 0.f;
            if ((unsigned)ir < (unsigned)H && (unsigned)ic < (unsigned)W)
                v = xc[ir * W + ic];
            lds[r * LDS_STRIDE + c] = v;         // zero halo == validity mask
        }
    }
    __syncthreads();

    // ---- thread -> pixels: fixed wo, rows row0 + 8j (j = 0..7) ----
    const int wo   = tid & 127;
    const int row0 = tid >> 7;                   // 0..7

    // d per owned pixel, loaded once (8 VGPRs)
    const float* __restrict__ dmg = dmap + (size_t)(b * G + g) * HoWo + ho0 * Wo;
    float d[8];
#pragma unroll
    for (int j = 0; j < 8; ++j)
        d[j] = dmg[(row0 + 8 * j) * Wo + wo];

    // block's 9 planes are CONSECUTIVE in out: base plane = (g*Cg+cg)*KK
    float* __restrict__ outc = out
        + ((size_t)(b * C + g * Cg + cg) * KK) * HoWo
        + (size_t)(ho0 * Wo);

    const float wof = (float)wo;

#pragma unroll
    for (int kh = 0; kh < K; ++kh) {
#pragma unroll
        for (int kw = 0; kw < K; ++kw) {
            float* __restrict__ op = outc + (size_t)(kh * K + kw) * HoWo;
#pragma unroll
            for (int j = 0; j < 8; ++j) {
                // region coords: row 0 = image row ho0-1, col 0 = image col -1
                // ph_reg = (ho - ho0) + kh*d ; pw_reg = wo + kw*d
                const float ph = (float)(row0 + 8 * j) + (float)kh * d[j];
                const float pw = wof + (float)kw * d[j];
                const int   r  = (int)ph;                  // 0..68
                const int   c  = (int)pw;                  // 0..132
                const float lh = ph - (float)r;
                const float lw = pw - (float)c;

                const float* __restrict__ l = lds + (r * LDS_STRIDE + c);
                const float v00 = l[0];
                const float v01 = l[1];
                const float v10 = l[LDS_STRIDE];
                const float v11 = l[LDS_STRIDE + 1];

                const float top = v00 + lw * (v01 - v00);
                const float bot = v10 + lw * (v11 - v10);
                op[(row0 + 8 * j) * Wo + wo] = top + lh * (bot - top);
            }
        }
    }
}

extern "C" void kernel_launch(void* const* d_in, const int* in_sizes, int n_in,
                              void* d_out, int out_size, void* d_ws, size_t ws_size,
                              hipStream_t stream) {
    const float* x    = (const float*)d_in[0];
    const float* dmap = (const float*)d_in[1];
    float* out = (float*)d_out;

    const int grid = B * G * Cg * (Ho / TILE_H);   // 512 = 2 blocks/CU
    ddu_kernel<<<grid, NTHREADS, 0, stream>>>(x, dmap, out);
}

// Round 8
// 169.429 us; speedup vs baseline: 1.1649x; 1.1649x over previous
//
#include <hip/hip_runtime.h>

// DynamicDilationUnfold: B=4, C=64, H=W=128, G=4, Cg=16, K=3, stride=1, pad=1.
// out[b][((g*Cg+cg)*K+kh)*K+kw][ho*Wo+wo], fp32.
//
// R12 = R11 with the compile fix: __builtin_nontemporal_store requires a
// clang vector type, not HIP's float2 class -> use ext_vector_type(2).
//
// Experiment (unchanged): single-variable A/B on the best kernel (R8,
// 74.7us kernel / 164.3 graded): flip output stores to NONTEMPORAL only.
// Store GEOMETRY exonerated (256B..16KiB runs, consecutive-plane regions,
// all at 32w/CU: no gain or worse). Theory: ~576 concurrently-dirty
// 64KiB-strided plane streams thrash L2/L3 dirty-line management (~2.3 TB/s
// drain); full-line nt streaming bypasses allocation -> near fill rate.
// Prediction: kernel 75 -> 40-55us (graded ~130-148) if right; neutral ->
// cache policy exonerated, next = LDS-bounce sequential streamer; worse ->
// nt bad even full-line, revert store path to R8.
//
// Structure (unchanged from R8): tile 16x128 full-width, CPB=4, 1024 thr,
// __launch_bounds__(1024,8) = 64-VGPR cap, 47.5 KB LDS, 2 blocks/CU =
// 32 waves/CU; per plane each wave stores one full 512-B row.

typedef float f32x2 __attribute__((ext_vector_type(2)));

constexpr int B  = 4;
constexpr int C  = 64;
constexpr int H  = 128;
constexpr int W  = 128;
constexpr int G  = 4;
constexpr int Cg = C / G;            // 16
constexpr int K  = 3;
constexpr int KK = K * K;
constexpr int Ho = 128;
constexpr int Wo = 128;
constexpr int HW = H * W;
constexpr int HoWo = Ho * Wo;

constexpr int TILE_H = 16;           // rows per block, full 128-col width
constexpr int CPB    = 4;            // channels per block
constexpr int REG_H  = 22;           // region rows: image ro0-1 .. ro0+20
constexpr int REG_W  = 134;          // region cols: image -1 .. 132
constexpr int LDS_STRIDE = 135;      // odd stride -> bank-decorrelated
constexpr int CH_STRIDE  = REG_H * LDS_STRIDE;   // 2970 dwords per channel
constexpr int NSTAGE     = CPB * CH_STRIDE;      // 11880 dwords = 47,520 B
constexpr int NTHREADS   = 1024;

__global__ __launch_bounds__(NTHREADS, 8) void ddu_kernel(
    const float* __restrict__ x,      // (B, C, H, W)
    const float* __restrict__ dmap,   // (B, G, H, W)
    float* __restrict__ out)          // (B, C*K*K, Ho*Wo)
{
    __shared__ float lds[NSTAGE];                // 47,520 B -> 2 blocks/CU

    const int tid = threadIdx.x;
    const int bid = blockIdx.x;                  // 512 = b(4) g(4) chunk(4) rt(8)
    const int rt    = bid & 7;
    const int chunk = (bid >> 3) & 3;
    const int g     = (bid >> 5) & 3;
    const int b     = bid >> 7;

    const int ro0 = rt * TILE_H;
    const int cgb = chunk * CPB;

    const float* __restrict__ xg = x + (size_t)(b * C + g * Cg + cgb) * HW;

    // ---- stage: channel-planar scalar LDS, coalesced dword loads, zero halo ----
#pragma unroll
    for (int it = 0; it < (NSTAGE + NTHREADS - 1) / NTHREADS; ++it) {
        const int p = it * NTHREADS + tid;
        if (p < NSTAGE) {
            const int ch  = p / CH_STRIDE;
            const int rem = p - ch * CH_STRIDE;
            const int rr  = rem / LDS_STRIDE;
            const int cc  = rem - rr * LDS_STRIDE;
            const int ir  = ro0 - 1 + rr;
            const int ic  = cc - 1;
            float v = 0.f;
            if ((unsigned)ir < (unsigned)H && (unsigned)ic < (unsigned)W && cc < REG_W)
                v = xg[(size_t)ch * HW + ir * W + ic];
            lds[p] = v;                          // zero halo == validity mask
        }
    }
    __syncthreads();

    // ---- compute: each thread owns 2 adjacent wo; wave = one full row ----
    const int wi2 = tid & 63;                    // wo-pair 0..63 (full 128 cols)
    const int hi  = tid >> 6;                    // 0..15
    const int ho  = ro0 + hi;
    const int wo  = wi2 * 2;

    const float2 dv = *(const float2*)&dmap[(size_t)(b * G + g) * HoWo + ho * Wo + wo];
    const float d0 = dv.x;
    const float d1 = dv.y;

    float* __restrict__ outb = out
        + (size_t)((b * C + g * Cg + cgb) * KK) * HoWo
        + (size_t)(ho * Wo + wo);

    const float col0 = (float)wo;                // region col of subpixel 0
    const float col1 = (float)(wo + 1);
    const float rowf = (float)hi;                // region row coordinate base

#pragma unroll
    for (int kh = 0; kh < K; ++kh) {
        const float ph0 = rowf + (float)kh * d0;
        const float ph1 = rowf + (float)kh * d1;
        const int   r0  = (int)ph0;              // <= 20
        const int   r1  = (int)ph1;
        const float lh0 = ph0 - (float)r0;
        const float lh1 = ph1 - (float)r1;
        const float mh0 = 1.f - lh0;
        const float mh1 = 1.f - lh1;

#pragma unroll
        for (int kw = 0; kw < K; ++kw) {
            const float pw0 = col0 + (float)kw * d0;
            const float pw1 = col1 + (float)kw * d1;
            const int   c0  = (int)pw0;          // <= 132
            const int   c1  = (int)pw1;
            const float lw0 = pw0 - (float)c0;
            const float lw1 = pw1 - (float)c1;

            const float a00 = mh0 * (1.f - lw0);
            const float a01 = mh0 * lw0;
            const float a10 = lh0 * (1.f - lw0);
            const float a11 = lh0 * lw0;

            const float b00 = mh1 * (1.f - lw1);
            const float b01 = mh1 * lw1;
            const float b10 = lh1 * (1.f - lw1);
            const float b11 = lh1 * lw1;

            const int base0 = r0 * LDS_STRIDE + c0;
            const int base1 = r1 * LDS_STRIDE + c1;

            float* __restrict__ o = outb + (size_t)(kh * K + kw) * HoWo;

#pragma unroll
            for (int ch = 0; ch < CPB; ++ch) {
                const float* __restrict__ l  = lds + ch * CH_STRIDE;
                const float* __restrict__ l0 = l + base0;
                const float* __restrict__ l1 = l + base1;
                f32x2 v;
                v.x = a00 * l0[0] + a01 * l0[1]
                    + a10 * l0[LDS_STRIDE] + a11 * l0[LDS_STRIDE + 1];
                v.y = b00 * l1[0] + b01 * l1[1]
                    + b10 * l1[LDS_STRIDE] + b11 * l1[LDS_STRIDE + 1];
                // single change vs R8: nontemporal full-line streaming store
                __builtin_nontemporal_store(v, (f32x2*)(o + (size_t)ch * (KK * HoWo)));
            }
        }
    }
}

extern "C" void kernel_launch(void* const* d_in, const int* in_sizes, int n_in,
                              void* d_out, int out_size, void* d_ws, size_t ws_size,
                              hipStream_t stream) {
    const float* x    = (const float*)d_in[0];
    const float* dmap = (const float*)d_in[1];
    float* out = (float*)d_out;

    const int grid = B * G * (Cg / CPB) * (Ho / TILE_H);   // 512 = 2 blocks/CU
    ddu_kernel<<<grid, NTHREADS, 0, stream>>>(x, dmap, out);
}